// Round 5
// baseline (2426.515 us; speedup 1.0000x reference)
//
#include <hip/hip_runtime.h>
#include <math.h>

#define NN 100000
#define NE 3200000
#define BSH 5
#define BSZ 32                        // dst-nodes per bucket
#define NBKT 3125                     // NN / BSZ exactly
#define TILE 4096
#define NTB 782                       // ceil(NE / TILE)
#define AST 65                        // acc row stride (odd -> bank spread)

#define FMA4(a, s, v) { (a).x += (s)*(v).x; (a).y += (s)*(v).y; (a).z += (s)*(v).z; (a).w += (s)*(v).w; }

__device__ __forceinline__ unsigned bf16rn(float f) {
    unsigned u = __float_as_uint(f);
    return (u + 0x7fffu + ((u >> 16) & 1u)) >> 16;
}

// ---------------- bucket histogram
__global__ __launch_bounds__(256) void bhist_k(const int* __restrict__ ei, int* __restrict__ bhist) {
    __shared__ int h[NBKT];
    int t = threadIdx.x;
    for (int j = t; j < NBKT; j += 256) h[j] = 0;
    __syncthreads();
    int e0 = blockIdx.x * TILE + t;
    #pragma unroll
    for (int i = 0; i < 16; i++) {
        int e = e0 + i * 256;
        if (e < NE) atomicAdd(&h[ei[NE + e] >> BSH], 1);
    }
    __syncthreads();
    for (int j = t; j < NBKT; j += 256) if (h[j]) atomicAdd(&bhist[j], h[j]);
}

// ---------------- scan NBKT counts -> offsets + cursors (1 block, 13 elems/thread)
__global__ __launch_bounds__(256) void bscan_k(const int* __restrict__ bhist,
                                               int* __restrict__ boff, int* __restrict__ bcur) {
    __shared__ int ps[256];
    int t = threadIdx.x;
    int v[13]; int sum = 0;
    #pragma unroll
    for (int i = 0; i < 13; i++) {
        int j = t * 13 + i;
        v[i] = (j < NBKT) ? bhist[j] : 0;
        sum += v[i];
    }
    ps[t] = sum;
    __syncthreads();
    for (int ofs = 1; ofs < 256; ofs <<= 1) {
        int a = (t >= ofs) ? ps[t - ofs] : 0;
        __syncthreads();
        ps[t] += a;
        __syncthreads();
    }
    int run = ps[t] - sum;
    #pragma unroll
    for (int i = 0; i < 13; i++) {
        int j = t * 13 + i;
        if (j < NBKT) { boff[j] = run; bcur[j] = run; }
        run += v[i];
    }
}

// ---------------- bucket scatter: contiguous runs per (tile-block, bucket)
__global__ __launch_bounds__(256) void bscatter_k(const int* __restrict__ ei, const float* __restrict__ ea,
                                                  int* __restrict__ bcur, int2* __restrict__ pk) {
    __shared__ int h[NBKT];
    __shared__ int base[NBKT];
    int t = threadIdx.x;
    for (int j = t; j < NBKT; j += 256) h[j] = 0;
    __syncthreads();
    int e0 = blockIdx.x * TILE + t;
    int pck[16], bk[16], rk[16];
    float uu[16];
    #pragma unroll
    for (int i = 0; i < 16; i++) {
        int e = e0 + i * 256;
        bk[i] = -1;
        if (e < NE) {
            int s = ei[e];
            int d = ei[NE + e];
            uu[i] = fminf(fmaxf(ea[e], 0.f), 1.f);
            bk[i] = d >> BSH;
            pck[i] = (s << BSH) | (d & (BSZ - 1));     // src 17b | dst-local 5b
            rk[i] = atomicAdd(&h[bk[i]], 1);
        }
    }
    __syncthreads();
    for (int j = t; j < NBKT; j += 256) base[j] = h[j] ? atomicAdd(&bcur[j], h[j]) : 0;
    __syncthreads();
    #pragma unroll
    for (int i = 0; i < 16; i++)
        if (bk[i] >= 0) pk[base[bk[i]] + rk[i]] = make_int2(pck[i], __float_as_int(uu[i]));
}

// ---------------- prep1: xb = bf16(x), xr = x@R1 + b1
__global__ __launch_bounds__(256) void prep1_k(
    const float* __restrict__ x, const float* __restrict__ R, const float* __restrict__ b,
    unsigned* __restrict__ xb, float* __restrict__ xr)
{
    __shared__ float Rs[1024];
    __shared__ float xs[32 * 33];
    int t = threadIdx.x;
    for (int i = t; i < 1024; i += 256) Rs[i] = R[i];
    int nb = blockIdx.x * 32;
    for (int i = t; i < 1024; i += 256) {
        int n = nb + (i >> 5);
        xs[(i >> 5) * 33 + (i & 31)] = (n < NN) ? x[n * 32 + (i & 31)] : 0.f;
    }
    __syncthreads();
    int local = t >> 3, c = t & 7;
    int n = nb + local;
    float4 a2 = make_float4(0.f, 0.f, 0.f, 0.f);
    #pragma unroll
    for (int k = 0; k < 32; k++) {
        float xk = xs[local * 33 + k];
        float4 r = ((const float4*)Rs)[k * 8 + c];
        FMA4(a2, xk, r);
    }
    if (n < NN) {
        float4 bb = ((const float4*)b)[c & 7];
        a2.x += bb.x; a2.y += bb.y; a2.z += bb.z; a2.w += bb.w;
        ((float4*)xr)[n * 8 + c] = a2;
        // bf16 row of x: lane c holds features 4c..4c+3 from LDS
        float f0 = xs[local * 33 + c * 4 + 0];
        float f1 = xs[local * 33 + c * 4 + 1];
        float f2 = xs[local * 33 + c * 4 + 2];
        float f3 = xs[local * 33 + c * 4 + 3];
        uint2 pkd;
        pkd.x = bf16rn(f0) | (bf16rn(f1) << 16);
        pkd.y = bf16rn(f2) | (bf16rn(f3) << 16);
        ((uint2*)xb)[n * 8 + c] = pkd;
    }
}

// ---------------- agg1: gather xb rows (1 line/edge), T/B sums in LDS, epilogue transform
__global__ __launch_bounds__(256) void agg1_k(
    const int* __restrict__ boff, const int* __restrict__ bhist, const int2* __restrict__ pk,
    const unsigned* __restrict__ xb, const float* __restrict__ W,   // W:[2,32,32]
    const float* __restrict__ xr, unsigned* __restrict__ hb)
{
    __shared__ float accA[BSZ * AST];   // T = sum x
    __shared__ float accB[BSZ * AST];   // B = sum u*x
    __shared__ float Wc[2048];          // [W0 ; W1-W0] as [64][32]
    __shared__ int cnt[BSZ];
    int t = threadIdx.x;
    for (int i = t; i < 1024; i += 256) {
        float w0 = W[i];
        Wc[i] = w0;
        Wc[1024 + i] = W[1024 + i] - w0;
    }
    for (int j = t; j < BSZ * AST; j += 256) { accA[j] = 0.f; accB[j] = 0.f; }
    if (t < BSZ) cnt[t] = 0;
    __syncthreads();

    int bkt = blockIdx.x;
    int st = boff[bkt], ne = bhist[bkt];
    int c = t & 3, slot = t >> 2;                 // 4 lanes/edge, 64 edges in flight
    const uint4* x4 = (const uint4*)xb;
    uint4 zz = make_uint4(0, 0, 0, 0);

    int i0 = slot;
    int2 p0 = (i0 < ne) ? pk[st + i0] : make_int2(-1, 0);
    uint4 v0 = (p0.x >= 0) ? x4[(size_t)(p0.x >> BSH) * 4 + c] : zz;
    int i1 = i0 + 64;
    int2 p1 = (i1 < ne) ? pk[st + i1] : make_int2(-1, 0);
    uint4 v1 = (p1.x >= 0) ? x4[(size_t)(p1.x >> BSH) * 4 + c] : zz;
    int i2 = i1 + 64;
    int2 p2 = (i2 < ne) ? pk[st + i2] : make_int2(-1, 0);

    while (true) {
        uint4 v2 = (p2.x >= 0) ? x4[(size_t)(p2.x >> BSH) * 4 + c] : zz;
        int i3 = i2 + 64;
        int2 p3 = (i3 < ne) ? pk[st + i3] : make_int2(-1, 0);
        if (p0.x >= 0) {
            int dl = p0.x & (BSZ - 1);
            float u = __int_as_float(p0.y);
            float f[8];
            f[0] = __uint_as_float(v0.x << 16); f[1] = __uint_as_float(v0.x & 0xffff0000u);
            f[2] = __uint_as_float(v0.y << 16); f[3] = __uint_as_float(v0.y & 0xffff0000u);
            f[4] = __uint_as_float(v0.z << 16); f[5] = __uint_as_float(v0.z & 0xffff0000u);
            f[6] = __uint_as_float(v0.w << 16); f[7] = __uint_as_float(v0.w & 0xffff0000u);
            float* pa = &accA[dl * AST + 8 * c];
            float* pb = &accB[dl * AST + 8 * c];
            #pragma unroll
            for (int j = 0; j < 8; j++) {
                atomicAdd(pa + j, f[j]);
                atomicAdd(pb + j, u * f[j]);
            }
            if (c == 0) atomicAdd(&cnt[dl], 1);
        }
        if (i1 >= ne) break;
        p0 = p1; v0 = v1; p1 = p2; v1 = v2; p2 = p3;
        i1 = i2; i2 = i3;
    }
    __syncthreads();

    // epilogue: h = relu((T@W0 + B@(W1-W0)) / max(cnt,1) + xr), write bf16
    int row = t >> 3, cc = t & 7;                 // 32 nodes x 8 lanes
    int n = bkt * BSZ + row;
    float inv = 1.f / fmaxf((float)cnt[row], 1.f);
    float4 acc = make_float4(0.f, 0.f, 0.f, 0.f);
    #pragma unroll
    for (int k = 0; k < 32; k++) {
        float sa = accA[row * AST + k];
        float4 w = ((const float4*)Wc)[k * 8 + cc];
        FMA4(acc, sa, w);
    }
    #pragma unroll
    for (int k = 0; k < 32; k++) {
        float sb = accB[row * AST + k];
        float4 w = ((const float4*)Wc)[(32 + k) * 8 + cc];
        FMA4(acc, sb, w);
    }
    float4 r = ((const float4*)xr)[n * 8 + cc];
    float h0 = fmaxf(acc.x * inv + r.x, 0.f);
    float h1 = fmaxf(acc.y * inv + r.y, 0.f);
    float h2 = fmaxf(acc.z * inv + r.z, 0.f);
    float h3 = fmaxf(acc.w * inv + r.w, 0.f);
    uint2 pkd;
    pkd.x = bf16rn(h0) | (bf16rn(h1) << 16);
    pkd.y = bf16rn(h2) | (bf16rn(h3) << 16);
    ((uint2*)hb)[n * 8 + cc] = pkd;
}

// ---------------- prep2: hr = h@R2 + b2 (h read as bf16)
__global__ __launch_bounds__(256) void prep2_k(
    const unsigned* __restrict__ hb, const float* __restrict__ R, const float* __restrict__ b,
    float* __restrict__ hr)
{
    __shared__ float Rs[512];
    __shared__ float xs[64 * 33];
    int t = threadIdx.x;
    for (int i = t; i < 512; i += 256) Rs[i] = R[i];
    int nb = blockIdx.x * 64;
    for (int i = t; i < 1024; i += 256) {
        int n = nb + (i >> 4), j = i & 15;
        unsigned v = (n < NN) ? hb[n * 16 + j] : 0u;
        xs[(i >> 4) * 33 + 2 * j]     = __uint_as_float(v << 16);
        xs[(i >> 4) * 33 + 2 * j + 1] = __uint_as_float(v & 0xffff0000u);
    }
    __syncthreads();
    int local = t >> 2, c = t & 3;
    int n = nb + local;
    float4 a = make_float4(0.f, 0.f, 0.f, 0.f);
    #pragma unroll
    for (int k = 0; k < 32; k++) {
        float xk = xs[local * 33 + k];
        float4 r = ((const float4*)Rs)[k * 4 + c];
        FMA4(a, xk, r);
    }
    if (n < NN) {
        float4 bb = ((const float4*)b)[c];
        a.x += bb.x; a.y += bb.y; a.z += bb.z; a.w += bb.w;
        ((float4*)hr)[n * 4 + c] = a;
    }
}

// ---------------- agg2: gather hb rows, T/B sums, epilogue transform + log_softmax
__global__ __launch_bounds__(256) void agg2_k(
    const int* __restrict__ boff, const int* __restrict__ bhist, const int2* __restrict__ pk,
    const unsigned* __restrict__ hb, const float* __restrict__ W,   // W:[2,32,16]
    const float* __restrict__ hr, float* __restrict__ out)
{
    __shared__ float accA[BSZ * AST];
    __shared__ float accB[BSZ * AST];
    __shared__ float Wc[1024];          // [W0 ; W1-W0] as [64][16]
    __shared__ int cnt[BSZ];
    int t = threadIdx.x;
    for (int i = t; i < 512; i += 256) {
        float w0 = W[i];
        Wc[i] = w0;
        Wc[512 + i] = W[512 + i] - w0;
    }
    for (int j = t; j < BSZ * AST; j += 256) { accA[j] = 0.f; accB[j] = 0.f; }
    if (t < BSZ) cnt[t] = 0;
    __syncthreads();

    int bkt = blockIdx.x;
    int st = boff[bkt], ne = bhist[bkt];
    int c = t & 3, slot = t >> 2;
    const uint4* x4 = (const uint4*)hb;
    uint4 zz = make_uint4(0, 0, 0, 0);

    int i0 = slot;
    int2 p0 = (i0 < ne) ? pk[st + i0] : make_int2(-1, 0);
    uint4 v0 = (p0.x >= 0) ? x4[(size_t)(p0.x >> BSH) * 4 + c] : zz;
    int i1 = i0 + 64;
    int2 p1 = (i1 < ne) ? pk[st + i1] : make_int2(-1, 0);
    uint4 v1 = (p1.x >= 0) ? x4[(size_t)(p1.x >> BSH) * 4 + c] : zz;
    int i2 = i1 + 64;
    int2 p2 = (i2 < ne) ? pk[st + i2] : make_int2(-1, 0);

    while (true) {
        uint4 v2 = (p2.x >= 0) ? x4[(size_t)(p2.x >> BSH) * 4 + c] : zz;
        int i3 = i2 + 64;
        int2 p3 = (i3 < ne) ? pk[st + i3] : make_int2(-1, 0);
        if (p0.x >= 0) {
            int dl = p0.x & (BSZ - 1);
            float u = __int_as_float(p0.y);
            float f[8];
            f[0] = __uint_as_float(v0.x << 16); f[1] = __uint_as_float(v0.x & 0xffff0000u);
            f[2] = __uint_as_float(v0.y << 16); f[3] = __uint_as_float(v0.y & 0xffff0000u);
            f[4] = __uint_as_float(v0.z << 16); f[5] = __uint_as_float(v0.z & 0xffff0000u);
            f[6] = __uint_as_float(v0.w << 16); f[7] = __uint_as_float(v0.w & 0xffff0000u);
            float* pa = &accA[dl * AST + 8 * c];
            float* pb = &accB[dl * AST + 8 * c];
            #pragma unroll
            for (int j = 0; j < 8; j++) {
                atomicAdd(pa + j, f[j]);
                atomicAdd(pb + j, u * f[j]);
            }
            if (c == 0) atomicAdd(&cnt[dl], 1);
        }
        if (i1 >= ne) break;
        p0 = p1; v0 = v1; p1 = p2; v1 = v2; p2 = p3;
        i1 = i2; i2 = i3;
    }
    __syncthreads();

    // epilogue: o = (T@W0 + B@(W1-W0))/max(cnt,1) + hr; log_softmax over 16 feats
    int nb = bkt * BSZ;
    for (int r0 = 0; r0 < BSZ; r0 += 16) {        // 16 nodes/pass, 16 lanes/node
        int row = r0 + (t >> 4), f = t & 15;
        int n = nb + row;
        float inv = 1.f / fmaxf((float)cnt[row], 1.f);
        float o = 0.f;
        #pragma unroll
        for (int k = 0; k < 32; k++) o += accA[row * AST + k] * Wc[k * 16 + f];
        #pragma unroll
        for (int k = 0; k < 32; k++) o += accB[row * AST + k] * Wc[(32 + k) * 16 + f];
        o = o * inv + hr[n * 16 + f];
        float m = o;
        #pragma unroll
        for (int ofs = 8; ofs; ofs >>= 1) m = fmaxf(m, __shfl_xor(m, ofs, 16));
        float sm = expf(o - m);
        #pragma unroll
        for (int ofs = 8; ofs; ofs >>= 1) sm += __shfl_xor(sm, ofs, 16);
        out[n * 16 + f] = o - (m + logf(sm));
    }
}

extern "C" void kernel_launch(void* const* d_in, const int* in_sizes, int n_in,
                              void* d_out, int out_size, void* d_ws, size_t ws_size,
                              hipStream_t stream) {
    const float* x     = (const float*)d_in[0];
    const int*   ei    = (const int*)d_in[1];
    const float* ea    = (const float*)d_in[2];
    const float* W1    = (const float*)d_in[3];
    const float* root1 = (const float*)d_in[4];
    const float* b1    = (const float*)d_in[5];
    const float* W2    = (const float*)d_in[6];
    const float* root2 = (const float*)d_in[7];
    const float* b2    = (const float*)d_in[8];
    float* out = (float*)d_out;

    float* ws = (float*)d_ws;
    int*  bhist = (int*)ws;                          // 4096 ints
    int*  boff  = bhist + 4096;
    int*  bcur  = boff + 4096;
    int2* pk    = (int2*)(ws + 12288);               // NE int2 (16B-aligned)
    unsigned* xb = (unsigned*)(ws + 12288 + 2 * (size_t)NE);  // NN*16 uints
    unsigned* hb = xb + (size_t)NN * 16;             // NN*16 uints
    float* xr = (float*)(hb + (size_t)NN * 16);      // NN*32
    float* hr = xr + (size_t)NN * 32;                // NN*16

    hipMemsetAsync(bhist, 0, NBKT * sizeof(int), stream);

    bhist_k   <<<NTB, 256, 0, stream>>>(ei, bhist);
    bscan_k   <<<1, 256, 0, stream>>>(bhist, boff, bcur);
    bscatter_k<<<NTB, 256, 0, stream>>>(ei, ea, bcur, pk);

    prep1_k<<<(NN + 31) / 32, 256, 0, stream>>>(x, root1, b1, xb, xr);
    agg1_k <<<NBKT, 256, 0, stream>>>(boff, bhist, pk, xb, W1, xr, hb);

    prep2_k<<<(NN + 63) / 64, 256, 0, stream>>>(hb, root2, b2, hr);
    agg2_k <<<NBKT, 256, 0, stream>>>(boff, bhist, pk, hb, W2, hr, out);
}

// Round 6
// 318.369 us; speedup vs baseline: 7.6217x; 7.6217x over previous
//
#include <hip/hip_runtime.h>
#include <math.h>

#define NN 100000
#define NE 3200000
#define BSH 6
#define BSZ 64                        // dst-nodes per bucket
#define NBKT 1563                     // ceil(NN / BSZ)
#define STILE 8192
#define NTBS 391                      // ceil(NE / STILE)
#define CHUNK 2048                    // edges staged/sorted per pass
#define TST 68                        // T/B LDS row stride (floats), 16B-aligned rows

#define FMA4(a, s, v) { (a).x += (s)*(v).x; (a).y += (s)*(v).y; (a).z += (s)*(v).z; (a).w += (s)*(v).w; }

__device__ __forceinline__ unsigned bf16rn(float f) {
    unsigned u = __float_as_uint(f);
    return (u + 0x7fffu + ((u >> 16) & 1u)) >> 16;
}
__device__ __forceinline__ float blo(unsigned w) { return __uint_as_float(w << 16); }
__device__ __forceinline__ float bhi(unsigned w) { return __uint_as_float(w & 0xffff0000u); }

// ---------------- bucket histogram
__global__ __launch_bounds__(256) void bhist_k(const int* __restrict__ ei, int* __restrict__ bhist) {
    __shared__ int h[NBKT];
    int t = threadIdx.x;
    for (int j = t; j < NBKT; j += 256) h[j] = 0;
    __syncthreads();
    int e0 = blockIdx.x * STILE + t;
    #pragma unroll
    for (int i = 0; i < 32; i++) {
        int e = e0 + i * 256;
        if (e < NE) atomicAdd(&h[ei[NE + e] >> BSH], 1);
    }
    __syncthreads();
    for (int j = t; j < NBKT; j += 256) if (h[j]) atomicAdd(&bhist[j], h[j]);
}

// ---------------- scan NBKT counts -> offsets + cursors (1 block, 7 elems/thread)
__global__ __launch_bounds__(256) void bscan_k(const int* __restrict__ bhist,
                                               int* __restrict__ boff, int* __restrict__ bcur) {
    __shared__ int ps[256];
    int t = threadIdx.x;
    int v[7]; int sum = 0;
    #pragma unroll
    for (int i = 0; i < 7; i++) {
        int j = t * 7 + i;
        v[i] = (j < NBKT) ? bhist[j] : 0;
        sum += v[i];
    }
    ps[t] = sum;
    __syncthreads();
    for (int ofs = 1; ofs < 256; ofs <<= 1) {
        int a = (t >= ofs) ? ps[t - ofs] : 0;
        __syncthreads();
        ps[t] += a;
        __syncthreads();
    }
    int run = ps[t] - sum;
    #pragma unroll
    for (int i = 0; i < 7; i++) {
        int j = t * 7 + i;
        if (j < NBKT) { boff[j] = run; bcur[j] = run; }
        run += v[i];
    }
}

// ---------------- bucket scatter: two-pass over an 8192-edge tile
__global__ __launch_bounds__(256) void bscatter_k(const int* __restrict__ ei, const float* __restrict__ ea,
                                                  int* __restrict__ bcur, int2* __restrict__ pk) {
    __shared__ int h[NBKT];
    __shared__ int h2[NBKT];
    __shared__ int base[NBKT];
    int t = threadIdx.x;
    for (int j = t; j < NBKT; j += 256) { h[j] = 0; h2[j] = 0; }
    __syncthreads();
    int e0 = blockIdx.x * STILE + t;
    #pragma unroll
    for (int i = 0; i < 32; i++) {
        int e = e0 + i * 256;
        if (e < NE) atomicAdd(&h[ei[NE + e] >> BSH], 1);
    }
    __syncthreads();
    for (int j = t; j < NBKT; j += 256) base[j] = h[j] ? atomicAdd(&bcur[j], h[j]) : 0;
    __syncthreads();
    #pragma unroll
    for (int i = 0; i < 32; i++) {
        int e = e0 + i * 256;
        if (e < NE) {
            int s = ei[e];
            int d = ei[NE + e];
            float u = fminf(fmaxf(ea[e], 0.f), 1.f);
            int bk = d >> BSH;
            int r = atomicAdd(&h2[bk], 1);
            pk[base[bk] + r] = make_int2((s << BSH) | (d & (BSZ - 1)), __float_as_int(u));
        }
    }
}

// ---------------- prep1: xb = bf16(x), xr = x@R1 + b1
__global__ __launch_bounds__(256) void prep1_k(
    const float* __restrict__ x, const float* __restrict__ R, const float* __restrict__ b,
    unsigned* __restrict__ xb, float* __restrict__ xr)
{
    __shared__ float Rs[1024];
    __shared__ float xs[32 * 33];
    int t = threadIdx.x;
    for (int i = t; i < 1024; i += 256) Rs[i] = R[i];
    int nb = blockIdx.x * 32;
    for (int i = t; i < 1024; i += 256) {
        int n = nb + (i >> 5);
        xs[(i >> 5) * 33 + (i & 31)] = (n < NN) ? x[n * 32 + (i & 31)] : 0.f;
    }
    __syncthreads();
    int local = t >> 3, c = t & 7;
    int n = nb + local;
    float4 a2 = make_float4(0.f, 0.f, 0.f, 0.f);
    #pragma unroll
    for (int k = 0; k < 32; k++) {
        float xk = xs[local * 33 + k];
        float4 r = ((const float4*)Rs)[k * 8 + c];
        FMA4(a2, xk, r);
    }
    if (n < NN) {
        float4 bb = ((const float4*)b)[c];
        a2.x += bb.x; a2.y += bb.y; a2.z += bb.z; a2.w += bb.w;
        ((float4*)xr)[n * 8 + c] = a2;
        float f0 = xs[local * 33 + c * 4 + 0];
        float f1 = xs[local * 33 + c * 4 + 1];
        float f2 = xs[local * 33 + c * 4 + 2];
        float f3 = xs[local * 33 + c * 4 + 3];
        uint2 pkd;
        pkd.x = bf16rn(f0) | (bf16rn(f1) << 16);
        pkd.y = bf16rn(f2) | (bf16rn(f3) << 16);
        ((uint2*)xb)[n * 8 + c] = pkd;
    }
}

// ---------------- agg1: counting-sort edges in LDS, register T/B accumulate, epilogue GEMM
__global__ __launch_bounds__(256) void agg1_k(
    const int* __restrict__ boff, const int* __restrict__ bhist, const int2* __restrict__ pk,
    const unsigned* __restrict__ xb, const float* __restrict__ W,   // W:[2,32,32]
    const float* __restrict__ xr, unsigned* __restrict__ hb)
{
    __shared__ float Wc[2048];           // [W0 ; W1-W0] as [64][32]
    __shared__ int ccnt[BSZ], coff[BSZ], dcnt[BSZ];
    __shared__ __align__(16) char smraw[CHUNK * 8 > BSZ * TST * 4 ? CHUNK * 8 : BSZ * TST * 4];
    int2*  pks = (int2*)smraw;           // sorted edges (per chunk)
    float* tb  = (float*)smraw;          // reused for T/B in epilogue

    int t = threadIdx.x;
    for (int i = t; i < 1024; i += 256) {
        float w0 = W[i];
        Wc[i] = w0;
        Wc[1024 + i] = W[1024 + i] - w0;
    }
    if (t < BSZ) { ccnt[t] = 0; dcnt[t] = 0; }
    __syncthreads();

    int bkt = blockIdx.x;
    int st = boff[bkt], ne = bhist[bkt];
    int r = t >> 2, j = t & 3;           // 4 lanes/node, lane j: features 8j..8j+7
    const uint4* x4 = (const uint4*)xb;
    float T[8] = {0,0,0,0,0,0,0,0}, B[8] = {0,0,0,0,0,0,0,0};

    for (int base = 0; base < ne; base += CHUNK) {
        int2 er[8]; int rk8[8];
        #pragma unroll
        for (int i = 0; i < 8; i++) {
            int e = base + i * 256 + t;
            rk8[i] = -1;
            if (e < ne) {
                er[i] = pk[st + e];
                rk8[i] = atomicAdd(&ccnt[er[i].x & (BSZ - 1)], 1);
            }
        }
        __syncthreads();
        if (t < BSZ) {                    // wave-0 exclusive scan of 64 bins
            int v = ccnt[t], sc = v;
            #pragma unroll
            for (int ofs = 1; ofs < 64; ofs <<= 1) {
                int nn = __shfl_up(sc, ofs);
                if (t >= ofs) sc += nn;
            }
            coff[t] = sc - v;
            dcnt[t] += v;
        }
        __syncthreads();
        #pragma unroll
        for (int i = 0; i < 8; i++)
            if (rk8[i] >= 0) pks[coff[er[i].x & (BSZ - 1)] + rk8[i]] = er[i];
        __syncthreads();

        int cs = coff[r], cn = ccnt[r];
        int2 p = cn > 0 ? pks[cs] : make_int2(0, 0);
        uint4 v = cn > 0 ? x4[(size_t)(p.x >> BSH) * 4 + j] : make_uint4(0,0,0,0);
        for (int k = 0; k < cn; k++) {
            int2 pn = p; uint4 vn = v;
            if (k + 1 < cn) {
                pn = pks[cs + k + 1];
                vn = x4[(size_t)(pn.x >> BSH) * 4 + j];
            }
            float u = __int_as_float(p.y);
            float f0 = blo(v.x), f1 = bhi(v.x), f2 = blo(v.y), f3 = bhi(v.y);
            float f4 = blo(v.z), f5 = bhi(v.z), f6 = blo(v.w), f7 = bhi(v.w);
            T[0] += f0; B[0] += u * f0;  T[1] += f1; B[1] += u * f1;
            T[2] += f2; B[2] += u * f2;  T[3] += f3; B[3] += u * f3;
            T[4] += f4; B[4] += u * f4;  T[5] += f5; B[5] += u * f5;
            T[6] += f6; B[6] += u * f6;  T[7] += f7; B[7] += u * f7;
            p = pn; v = vn;
        }
        __syncthreads();
        if (t < BSZ) ccnt[t] = 0;
        __syncthreads();
    }

    // T/B -> LDS (tb row: [T(32) | B(32)], stride TST)
    ((float4*)(tb + r * TST + 8 * j))[0]      = make_float4(T[0], T[1], T[2], T[3]);
    ((float4*)(tb + r * TST + 8 * j))[1]      = make_float4(T[4], T[5], T[6], T[7]);
    ((float4*)(tb + r * TST + 32 + 8 * j))[0] = make_float4(B[0], B[1], B[2], B[3]);
    ((float4*)(tb + r * TST + 32 + 8 * j))[1] = make_float4(B[4], B[5], B[6], B[7]);
    __syncthreads();

    // epilogue: h = relu((T@W0 + B@(W1-W0))/max(deg,1) + xr) -> bf16
    #pragma unroll
    for (int r0 = 0; r0 < BSZ; r0 += 32) {
        int row = r0 + (t >> 3), cc = t & 7;
        int n = bkt * BSZ + row;
        float inv = 1.f / fmaxf((float)dcnt[row], 1.f);
        float4 acc = make_float4(0.f, 0.f, 0.f, 0.f);
        #pragma unroll
        for (int k = 0; k < 32; k++) {
            float sa = tb[row * TST + k];
            float4 w = ((const float4*)Wc)[k * 8 + cc];
            FMA4(acc, sa, w);
        }
        #pragma unroll
        for (int k = 0; k < 32; k++) {
            float sb = tb[row * TST + 32 + k];
            float4 w = ((const float4*)Wc)[(32 + k) * 8 + cc];
            FMA4(acc, sb, w);
        }
        if (n < NN) {
            float4 rr = ((const float4*)xr)[n * 8 + cc];
            float h0 = fmaxf(acc.x * inv + rr.x, 0.f);
            float h1 = fmaxf(acc.y * inv + rr.y, 0.f);
            float h2 = fmaxf(acc.z * inv + rr.z, 0.f);
            float h3 = fmaxf(acc.w * inv + rr.w, 0.f);
            uint2 pkd;
            pkd.x = bf16rn(h0) | (bf16rn(h1) << 16);
            pkd.y = bf16rn(h2) | (bf16rn(h3) << 16);
            ((uint2*)hb)[n * 8 + cc] = pkd;
        }
    }
}

// ---------------- prep2: hr = h@R2 + b2 (h read as bf16)
__global__ __launch_bounds__(256) void prep2_k(
    const unsigned* __restrict__ hb, const float* __restrict__ R, const float* __restrict__ b,
    float* __restrict__ hr)
{
    __shared__ float Rs[512];
    __shared__ float xs[64 * 33];
    int t = threadIdx.x;
    for (int i = t; i < 512; i += 256) Rs[i] = R[i];
    int nb = blockIdx.x * 64;
    for (int i = t; i < 1024; i += 256) {
        int n = nb + (i >> 4), j = i & 15;
        unsigned v = (n < NN) ? hb[n * 16 + j] : 0u;
        xs[(i >> 4) * 33 + 2 * j]     = blo(v);
        xs[(i >> 4) * 33 + 2 * j + 1] = bhi(v);
    }
    __syncthreads();
    int local = t >> 2, c = t & 3;
    int n = nb + local;
    float4 a = make_float4(0.f, 0.f, 0.f, 0.f);
    #pragma unroll
    for (int k = 0; k < 32; k++) {
        float xk = xs[local * 33 + k];
        float4 r = ((const float4*)Rs)[k * 4 + c];
        FMA4(a, xk, r);
    }
    if (n < NN) {
        float4 bb = ((const float4*)b)[c];
        a.x += bb.x; a.y += bb.y; a.z += bb.z; a.w += bb.w;
        ((float4*)hr)[n * 4 + c] = a;
    }
}

// ---------------- agg2: same sort+register scheme, epilogue -> log_softmax
__global__ __launch_bounds__(256) void agg2_k(
    const int* __restrict__ boff, const int* __restrict__ bhist, const int2* __restrict__ pk,
    const unsigned* __restrict__ hb, const float* __restrict__ W,   // W:[2,32,16]
    const float* __restrict__ hr, float* __restrict__ out)
{
    __shared__ float Wc[1024];           // [W0 ; W1-W0] as [64][16]
    __shared__ int ccnt[BSZ], coff[BSZ], dcnt[BSZ];
    __shared__ __align__(16) char smraw[CHUNK * 8 > BSZ * TST * 4 ? CHUNK * 8 : BSZ * TST * 4];
    int2*  pks = (int2*)smraw;
    float* tb  = (float*)smraw;

    int t = threadIdx.x;
    for (int i = t; i < 512; i += 256) {
        float w0 = W[i];
        Wc[i] = w0;
        Wc[512 + i] = W[512 + i] - w0;
    }
    if (t < BSZ) { ccnt[t] = 0; dcnt[t] = 0; }
    __syncthreads();

    int bkt = blockIdx.x;
    int st = boff[bkt], ne = bhist[bkt];
    int r = t >> 2, j = t & 3;
    const uint4* x4 = (const uint4*)hb;
    float T[8] = {0,0,0,0,0,0,0,0}, B[8] = {0,0,0,0,0,0,0,0};

    for (int base = 0; base < ne; base += CHUNK) {
        int2 er[8]; int rk8[8];
        #pragma unroll
        for (int i = 0; i < 8; i++) {
            int e = base + i * 256 + t;
            rk8[i] = -1;
            if (e < ne) {
                er[i] = pk[st + e];
                rk8[i] = atomicAdd(&ccnt[er[i].x & (BSZ - 1)], 1);
            }
        }
        __syncthreads();
        if (t < BSZ) {
            int v = ccnt[t], sc = v;
            #pragma unroll
            for (int ofs = 1; ofs < 64; ofs <<= 1) {
                int nn = __shfl_up(sc, ofs);
                if (t >= ofs) sc += nn;
            }
            coff[t] = sc - v;
            dcnt[t] += v;
        }
        __syncthreads();
        #pragma unroll
        for (int i = 0; i < 8; i++)
            if (rk8[i] >= 0) pks[coff[er[i].x & (BSZ - 1)] + rk8[i]] = er[i];
        __syncthreads();

        int cs = coff[r], cn = ccnt[r];
        int2 p = cn > 0 ? pks[cs] : make_int2(0, 0);
        uint4 v = cn > 0 ? x4[(size_t)(p.x >> BSH) * 4 + j] : make_uint4(0,0,0,0);
        for (int k = 0; k < cn; k++) {
            int2 pn = p; uint4 vn = v;
            if (k + 1 < cn) {
                pn = pks[cs + k + 1];
                vn = x4[(size_t)(pn.x >> BSH) * 4 + j];
            }
            float u = __int_as_float(p.y);
            float f0 = blo(v.x), f1 = bhi(v.x), f2 = blo(v.y), f3 = bhi(v.y);
            float f4 = blo(v.z), f5 = bhi(v.z), f6 = blo(v.w), f7 = bhi(v.w);
            T[0] += f0; B[0] += u * f0;  T[1] += f1; B[1] += u * f1;
            T[2] += f2; B[2] += u * f2;  T[3] += f3; B[3] += u * f3;
            T[4] += f4; B[4] += u * f4;  T[5] += f5; B[5] += u * f5;
            T[6] += f6; B[6] += u * f6;  T[7] += f7; B[7] += u * f7;
            p = pn; v = vn;
        }
        __syncthreads();
        if (t < BSZ) ccnt[t] = 0;
        __syncthreads();
    }

    ((float4*)(tb + r * TST + 8 * j))[0]      = make_float4(T[0], T[1], T[2], T[3]);
    ((float4*)(tb + r * TST + 8 * j))[1]      = make_float4(T[4], T[5], T[6], T[7]);
    ((float4*)(tb + r * TST + 32 + 8 * j))[0] = make_float4(B[0], B[1], B[2], B[3]);
    ((float4*)(tb + r * TST + 32 + 8 * j))[1] = make_float4(B[4], B[5], B[6], B[7]);
    __syncthreads();

    // epilogue: o = (T@W0 + B@(W1-W0))/max(deg,1) + hr; log_softmax over 16 feats
    #pragma unroll
    for (int r0 = 0; r0 < BSZ; r0 += 16) {
        int row = r0 + (t >> 4), f = t & 15;
        int n = bkt * BSZ + row;
        float inv = 1.f / fmaxf((float)dcnt[row], 1.f);
        float o = 0.f;
        #pragma unroll
        for (int k = 0; k < 32; k++) o += tb[row * TST + k] * Wc[k * 16 + f];
        #pragma unroll
        for (int k = 0; k < 32; k++) o += tb[row * TST + 32 + k] * Wc[(32 + k) * 16 + f];
        if (n < NN) {
            o = o * inv + hr[n * 16 + f];
            float m = o;
            #pragma unroll
            for (int ofs = 8; ofs; ofs >>= 1) m = fmaxf(m, __shfl_xor(m, ofs, 16));
            float sm = expf(o - m);
            #pragma unroll
            for (int ofs = 8; ofs; ofs >>= 1) sm += __shfl_xor(sm, ofs, 16);
            out[n * 16 + f] = o - (m + logf(sm));
        }
    }
}

extern "C" void kernel_launch(void* const* d_in, const int* in_sizes, int n_in,
                              void* d_out, int out_size, void* d_ws, size_t ws_size,
                              hipStream_t stream) {
    const float* x     = (const float*)d_in[0];
    const int*   ei    = (const int*)d_in[1];
    const float* ea    = (const float*)d_in[2];
    const float* W1    = (const float*)d_in[3];
    const float* root1 = (const float*)d_in[4];
    const float* b1    = (const float*)d_in[5];
    const float* W2    = (const float*)d_in[6];
    const float* root2 = (const float*)d_in[7];
    const float* b2    = (const float*)d_in[8];
    float* out = (float*)d_out;

    float* ws = (float*)d_ws;
    int*  bhist = (int*)ws;                          // 2048 ints
    int*  boff  = bhist + 2048;
    int*  bcur  = boff + 2048;
    int2* pk    = (int2*)(ws + 6144);                // NE int2
    unsigned* xb = (unsigned*)(ws + 6144 + 2 * (size_t)NE);   // NN*16
    unsigned* hb = xb + (size_t)NN * 16;             // NN*16
    float* xr = (float*)(hb + (size_t)NN * 16);      // NN*32
    float* hr = xr + (size_t)NN * 32;                // NN*16

    hipMemsetAsync(bhist, 0, NBKT * sizeof(int), stream);

    bhist_k   <<<NTBS, 256, 0, stream>>>(ei, bhist);
    bscan_k   <<<1, 256, 0, stream>>>(bhist, boff, bcur);
    bscatter_k<<<NTBS, 256, 0, stream>>>(ei, ea, bcur, pk);

    prep1_k<<<(NN + 31) / 32, 256, 0, stream>>>(x, root1, b1, xb, xr);
    agg1_k <<<NBKT, 256, 0, stream>>>(boff, bhist, pk, xb, W1, xr, hb);

    prep2_k<<<(NN + 63) / 64, 256, 0, stream>>>(hb, root2, b2, hr);
    agg2_k <<<NBKT, 256, 0, stream>>>(boff, bhist, pk, hb, W2, hr, out);
}